// Round 16
// baseline (149.137 us; speedup 1.0000x reference)
//
#include <hip/hip_runtime.h>
#include <hip/hip_bf16.h>
#include <math.h>

#define T_SEQ 4096
#define NH 16
#define HD 64
#define C_DIM 1024
#define N_QKV 3072

typedef __bf16 bf16x8 __attribute__((ext_vector_type(8)));
typedef __bf16 bf16x2 __attribute__((ext_vector_type(2)));
typedef float f32x4 __attribute__((ext_vector_type(4)));
typedef float f32x16 __attribute__((ext_vector_type(16)));
typedef unsigned short u16x8 __attribute__((ext_vector_type(8)));
typedef unsigned short u16x4 __attribute__((ext_vector_type(4)));
typedef unsigned int u32x4 __attribute__((ext_vector_type(4)));

__device__ __forceinline__ unsigned short f2bf(float f) {
  unsigned u = __builtin_bit_cast(unsigned, f);
  u += 0x7FFFu + ((u >> 16) & 1u);
  return (unsigned short)(u >> 16);
}

__device__ __forceinline__ bf16x8 lds_frag(const unsigned short* p) {
  return __builtin_bit_cast(bf16x8, *reinterpret_cast<const u16x8*>(p));
}

// async global->LDS, 16B per lane; LDS dest = wave-uniform base + lane*16
__device__ __forceinline__ void gload_lds16(const unsigned short* g, unsigned short* l) {
  __builtin_amdgcn_global_load_lds(
      (const __attribute__((address_space(1))) unsigned int*)(uintptr_t)(const void*)g,
      (__attribute__((address_space(3))) unsigned int*)(uintptr_t)(void*)l, 16, 0, 0);
}

// ---------------------------------------------------------------- convert ----
// Only weights now: x->bf16 is fused into GEMM1's A-staging.
__global__ void convert_kernel(const float* __restrict__ wqkv,
                               const float* __restrict__ wout,
                               unsigned short* __restrict__ wqkvb,
                               unsigned short* __restrict__ woutb) {
  const int NW = N_QKV * C_DIM;
  const int NO = C_DIM * C_DIM;
  int idx = blockIdx.x * blockDim.x + threadIdx.x;
  int i = idx * 4;
  if (i >= NW + NO) return;
  const float* src;
  unsigned short* dst;
  if (i < NW) { src = wqkv + i;        dst = wqkvb + i; }
  else        { src = wout + (i - NW); dst = woutb + (i - NW); }
  float4 v = *reinterpret_cast<const float4*>(src);
  u16x4 o;
  o[0] = f2bf(v.x); o[1] = f2bf(v.y); o[2] = f2bf(v.z); o[3] = f2bf(v.w);
  *reinterpret_cast<u16x4*>(dst) = o;
}

// ------------------------------------------------------------------- GEMM ----
// C[M][N] = A[M][K] * B[N][K]^T. B staged via global_load_lds width=16 with
// source-side XOR swizzle (proven). A staged the same way when bf16 (AF32=0),
// or reg-staged f32->cvt_pk->ds_write when AF32=1 (same LDS content).
// XCD-aware block swizzle (T1): grids are %8==0 -> bijective.
template <bool F32OUT, bool AF32>
__global__ __launch_bounds__(256) void gemm_bt(
    const void* __restrict__ Avoid, const unsigned short* __restrict__ Bm,
    unsigned short* __restrict__ Cb, float* __restrict__ Cf,
    const float* __restrict__ bias, int M, int N, int K,
    int scale_cols, float ascale) {
  __shared__ __align__(16) unsigned short As[128 * 64];
  __shared__ __align__(16) unsigned short Bs[128 * 64];
  const unsigned short* A16 = (const unsigned short*)Avoid;
  const float* A32 = (const float*)Avoid;
  const int tid = threadIdx.x;
  const int lane = tid & 63, wid = tid >> 6;
  const int l15 = lane & 15, g = lane >> 4;
  const int nbn = N >> 7;
  const int nwg = gridDim.x;
  const int swzb = (blockIdx.x & 7) * (nwg >> 3) + (blockIdx.x >> 3);
  const int bm = swzb / nbn, bn = swzb % nbn;
  const int wm = wid >> 1, wn = wid & 1;

  f32x4 acc[4][4];
  const f32x4 zero = {0.f, 0.f, 0.f, 0.f};
#pragma unroll
  for (int m = 0; m < 4; m++)
#pragma unroll
    for (int n = 0; n < 4; n++) acc[m][n] = zero;

  for (int k0 = 0; k0 < K; k0 += 64) {
    __syncthreads();
#pragma unroll
    for (int i = 0; i < 4; i++) {
      int c = tid + i * 256;            // 0..1023: LDS 16B-slot index (linear)
      int row = c >> 3, slot = c & 7;
      int col = slot ^ (row & 7);       // pre-swizzled global column
      if (AF32) {
        const float* ap = A32 + (size_t)(bm * 128 + row) * K + k0 + col * 8;
        float4 v0 = *reinterpret_cast<const float4*>(ap);
        float4 v1 = *reinterpret_cast<const float4*>(ap + 4);
        bf16x8 w = {(__bf16)v0.x, (__bf16)v0.y, (__bf16)v0.z, (__bf16)v0.w,
                    (__bf16)v1.x, (__bf16)v1.y, (__bf16)v1.z, (__bf16)v1.w};
        *reinterpret_cast<bf16x8*>(&As[c * 8]) = w;
      } else {
        gload_lds16(A16 + (size_t)(bm * 128 + row) * K + k0 + col * 8, &As[c * 8]);
      }
      gload_lds16(Bm + (size_t)(bn * 128 + row) * K + k0 + col * 8, &Bs[c * 8]);
    }
    __syncthreads();
#pragma unroll
    for (int kk = 0; kk < 2; kk++) {
      bf16x8 af[4], bfr[4];
#pragma unroll
      for (int m = 0; m < 4; m++) {
        int row = wm * 64 + m * 16 + l15;
        af[m] = lds_frag(reinterpret_cast<const unsigned short*>(
            reinterpret_cast<const char*>(As) + row * 128 + ((kk * 64 + g * 16) ^ ((l15 & 7) << 4))));
      }
#pragma unroll
      for (int n = 0; n < 4; n++) {
        int row = wn * 64 + n * 16 + l15;
        bfr[n] = lds_frag(reinterpret_cast<const unsigned short*>(
            reinterpret_cast<const char*>(Bs) + row * 128 + ((kk * 64 + g * 16) ^ ((l15 & 7) << 4))));
      }
#pragma unroll
      for (int m = 0; m < 4; m++)
#pragma unroll
        for (int n = 0; n < 4; n++)
          acc[m][n] = __builtin_amdgcn_mfma_f32_16x16x32_bf16(af[m], bfr[n], acc[m][n], 0, 0, 0);
    }
  }
#pragma unroll
  for (int m = 0; m < 4; m++) {
    int row0 = bm * 128 + wm * 64 + m * 16 + g * 4;
#pragma unroll
    for (int n = 0; n < 4; n++) {
      int col = bn * 128 + wn * 64 + n * 16 + l15;
      float bi = 0.f;
      if (F32OUT) bi = bias[col];
      float cs = (col < scale_cols) ? ascale : 1.0f;
#pragma unroll
      for (int r = 0; r < 4; r++) {
        float v = acc[m][n][r];
        if (F32OUT) Cf[(size_t)(row0 + r) * N + col] = v + bi;
        else        Cb[(size_t)(row0 + r) * N + col] = f2bf(v * cs);
      }
    }
  }
}

// -------------------------------------------------------------- attention ----
// (unchanged from round 15: swapped-QK^T, 32x32x16 MFMA, fixed-max softmax,
// 64 q-rows/wave, 2-way KV-split, immediate PV, permlane32_swap exchange,
// K dbuf [32x72] + V^T dbuf [64x40], (256,2) -> 104 VGPR no spill)
__global__ __launch_bounds__(256, 2) void attn_kernel(
    const unsigned short* __restrict__ qkv,   // [T][3072] bf16, q pre-scaled
    unsigned short* __restrict__ attn) {      // [T][1024] bf16
  __shared__ __align__(16) unsigned short smem[2 * 2 * 4864];   // 38912 B
  const int tid = threadIdx.x;
  const int lane = tid & 63, wid = tid >> 6;
  const int qw = wid & 1, str = wid >> 1;
  const int stid = qw * 64 + lane;
  const int l31 = lane & 31, hi = lane >> 5;
  const int sw = (blockIdx.x & 7) * 64 + (blockIdx.x >> 3);
  const int h = sw >> 5;
  const int qb = sw & 31;
  const int t0 = qb * 128 + qw * 64;
  const int q = l31;
  const int kvbase = str * (T_SEQ / 2);
  const int NT = (T_SEQ / 2) / 32;              // 64 tiles of 32 keys

  unsigned short* Sbase = &smem[str * 2 * 4864];

  const int krow = stid >> 2, ks = stid & 3;        // K: row 0..31, 32B slot
  const int kp = stid & 15, vd0 = (stid >> 4) * 8;  // V: keys 2kp,2kp+1; 8 d's

  bf16x8 qf[2][4];
#pragma unroll
  for (int j = 0; j < 2; j++)
#pragma unroll
    for (int ds = 0; ds < 4; ds++) {
      const unsigned short* p =
          qkv + (size_t)(t0 + j * 32 + q) * N_QKV + h * HD + ds * 16 + hi * 8;
      qf[j][ds] = __builtin_bit_cast(bf16x8, *reinterpret_cast<const u16x8*>(p));
    }

  float l_run[2] = {0.f, 0.f};
  f32x16 o[2][2];
  const f32x16 zero16 = {0.f};
  o[0][0] = zero16; o[0][1] = zero16; o[1][0] = zero16; o[1][1] = zero16;
  f32x16 minit;
#pragma unroll
  for (int i = 0; i < 16; i++) minit[i] = -4.0f;  // fixed softmax shift

  u16x8 kreg[2], vreg[2];
  {  // prologue: loads for this stream's tile 0
    const unsigned short* kb = qkv + (size_t)(kvbase + krow) * N_QKV + C_DIM + h * HD + ks * 16;
    kreg[0] = *reinterpret_cast<const u16x8*>(kb);
    kreg[1] = *reinterpret_cast<const u16x8*>(kb + 8);
    const unsigned short* vb = qkv + (size_t)(kvbase + 2 * kp) * N_QKV + 2 * C_DIM + h * HD + vd0;
    vreg[0] = *reinterpret_cast<const u16x8*>(vb);
    vreg[1] = *reinterpret_cast<const u16x8*>(vb + N_QKV);
  }

  for (int t = 0; t < NT; t++) {
    unsigned short* Kb = Sbase + (t & 1) * 4864;
    unsigned short* Vb = Kb + 2304;
    *reinterpret_cast<u16x8*>(&Kb[krow * 72 + ks * 16]) = kreg[0];
    *reinterpret_cast<u16x8*>(&Kb[krow * 72 + ks * 16 + 8]) = kreg[1];
#pragma unroll
    for (int jj = 0; jj < 8; jj++) {
      unsigned pk = (unsigned)vreg[0][jj] | ((unsigned)vreg[1][jj] << 16);
      *reinterpret_cast<unsigned*>(&Vb[(vd0 + jj) * 40 + 2 * kp]) = pk;
    }
    if (t < NT - 1) {
      const int kv0 = kvbase + (t + 1) * 32;
      const unsigned short* kb = qkv + (size_t)(kv0 + krow) * N_QKV + C_DIM + h * HD + ks * 16;
      kreg[0] = *reinterpret_cast<const u16x8*>(kb);
      kreg[1] = *reinterpret_cast<const u16x8*>(kb + 8);
      const unsigned short* vb = qkv + (size_t)(kv0 + 2 * kp) * N_QKV + 2 * C_DIM + h * HD + vd0;
      vreg[0] = *reinterpret_cast<const u16x8*>(vb);
      vreg[1] = *reinterpret_cast<const u16x8*>(vb + N_QKV);
    }
    __syncthreads();

    f32x16 s[2];
    s[0] = minit; s[1] = minit;
    __builtin_amdgcn_s_setprio(1);
#pragma unroll
    for (int ds = 0; ds < 4; ds++) {
      bf16x8 kf = lds_frag(&Kb[l31 * 72 + ds * 16 + hi * 8]);
      s[0] = __builtin_amdgcn_mfma_f32_32x32x16_bf16(kf, qf[0][ds], s[0], 0, 0, 0);
      s[1] = __builtin_amdgcn_mfma_f32_32x32x16_bf16(kf, qf[1][ds], s[1], 0, 0, 0);
    }
    __builtin_amdgcn_s_setprio(0);

    unsigned wA[2][8];
#pragma unroll
    for (int j = 0; j < 2; j++) {
      float psum[8];
#pragma unroll
      for (int i = 0; i < 8; i++) {
        float pa = __builtin_amdgcn_exp2f(s[j][2 * i]);
        float pb = __builtin_amdgcn_exp2f(s[j][2 * i + 1]);
        bf16x2 pk = {(__bf16)pa, (__bf16)pb};
        wA[j][i] = __builtin_bit_cast(unsigned, pk);
        psum[i] = pa + pb;
      }
#pragma unroll
      for (int i = 0; i < 4; i++) psum[i] += psum[i + 4];
      l_run[j] += (psum[0] + psum[2]) + (psum[1] + psum[3]);
#pragma unroll
      for (int base = 0; base < 8; base += 4)
#pragma unroll
        for (int k = 0; k < 2; k++) {
          unsigned A = wA[j][base + k];
          unsigned B = wA[j][base + k + 2];
          asm("v_permlane32_swap_b32 %0, %1" : "+v"(A), "+v"(B));
          wA[j][base + k]     = A;
          wA[j][base + k + 2] = B;
        }
    }

    u32x4 g00 = {wA[0][0], wA[0][1], wA[0][2], wA[0][3]};
    u32x4 g01 = {wA[0][4], wA[0][5], wA[0][6], wA[0][7]};
    u32x4 g10 = {wA[1][0], wA[1][1], wA[1][2], wA[1][3]};
    u32x4 g11 = {wA[1][4], wA[1][5], wA[1][6], wA[1][7]};
    bf16x8 pf00 = __builtin_bit_cast(bf16x8, g00);
    bf16x8 pf01 = __builtin_bit_cast(bf16x8, g01);
    bf16x8 pf10 = __builtin_bit_cast(bf16x8, g10);
    bf16x8 pf11 = __builtin_bit_cast(bf16x8, g11);
    __builtin_amdgcn_s_setprio(1);
#pragma unroll
    for (int dblk = 0; dblk < 2; dblk++) {
      bf16x8 vf0 = lds_frag(&Vb[(dblk * 32 + l31) * 40 + hi * 8]);
      bf16x8 vf1 = lds_frag(&Vb[(dblk * 32 + l31) * 40 + 16 + hi * 8]);
      o[0][dblk] = __builtin_amdgcn_mfma_f32_32x32x16_bf16(vf0, pf00, o[0][dblk], 0, 0, 0);
      o[0][dblk] = __builtin_amdgcn_mfma_f32_32x32x16_bf16(vf1, pf01, o[0][dblk], 0, 0, 0);
      o[1][dblk] = __builtin_amdgcn_mfma_f32_32x32x16_bf16(vf0, pf10, o[1][dblk], 0, 0, 0);
      o[1][dblk] = __builtin_amdgcn_mfma_f32_32x32x16_bf16(vf1, pf11, o[1][dblk], 0, 0, 0);
    }
    __builtin_amdgcn_s_setprio(0);
  }

  // ---- merge the 2 KV-split partials through LDS (fixed max -> direct add)
  float* ob = reinterpret_cast<float*>(&smem[0]);
  float* lb = ob + 8192;
  const int midx = qw * 64 + lane;
#pragma unroll
  for (int j = 0; j < 2; j++) {
    __syncthreads();
    if (str == 1) {
#pragma unroll
      for (int dblk = 0; dblk < 2; dblk++)
#pragma unroll
        for (int r = 0; r < 16; r++)
          ob[(dblk * 16 + r) * 128 + midx] = o[j][dblk][r];
      lb[midx] = l_run[j];
    }
    __syncthreads();
    if (str == 0) {
#pragma unroll
      for (int dblk = 0; dblk < 2; dblk++)
#pragma unroll
        for (int r = 0; r < 16; r++)
          o[j][dblk][r] += ob[(dblk * 16 + r) * 128 + midx];
      l_run[j] += lb[midx];
    }
  }

  // ---- epilogue: attn[t][h*64 + d] = O^T[d][q] / l
  if (str == 0) {
#pragma unroll
    for (int j = 0; j < 2; j++) {
      float lr = l_run[j];
      float inv = 1.f / (lr + __shfl_xor(lr, 32));
      const int t = t0 + j * 32 + q;
#pragma unroll
      for (int dblk = 0; dblk < 2; dblk++)
#pragma unroll
        for (int qd = 0; qd < 4; qd++) {
          u16x4 w;
#pragma unroll
          for (int i = 0; i < 4; i++) w[i] = f2bf(o[j][dblk][qd * 4 + i] * inv);
          *reinterpret_cast<u16x4*>(
              &attn[(size_t)t * C_DIM + h * HD + dblk * 32 + qd * 8 + hi * 4]) = w;
        }
    }
  }
}

// ----------------------------------------------------------------- launch ----
extern "C" void kernel_launch(void* const* d_in, const int* in_sizes, int n_in,
                              void* d_out, int out_size, void* d_ws, size_t ws_size,
                              hipStream_t stream) {
  const float* x     = (const float*)d_in[0];
  const float* w_qkv = (const float*)d_in[1];
  const float* w_out = (const float*)d_in[2];
  const float* b_out = (const float*)d_in[3];
  float* out = (float*)d_out;
  char* ws = (char*)d_ws;
  unsigned short* wqkvb = (unsigned short*)(ws + (8u << 20));
  unsigned short* woutb = (unsigned short*)(ws + (14u << 20));
  unsigned short* qkvb  = (unsigned short*)(ws + (16u << 20));
  unsigned short* attnb = (unsigned short*)(ws + (40u << 20));

  const float QSCALE = 0.125f * 1.44269504f;  // fold /sqrt(64) and log2e into q

  convert_kernel<<<4096, 256, 0, stream>>>(w_qkv, w_out, wqkvb, woutb);
  gemm_bt<false, true><<<768, 256, 0, stream>>>(x, wqkvb, qkvb, nullptr, nullptr,
                                                T_SEQ, N_QKV, C_DIM, C_DIM, QSCALE);
  attn_kernel<<<512, 256, 0, stream>>>(qkvb, attnb);
  gemm_bt<true, false><<<256, 256, 0, stream>>>(attnb, woutb, nullptr, out, b_out,
                                                T_SEQ, C_DIM, C_DIM, 0, 1.0f);
}

// Round 17
// 143.873 us; speedup vs baseline: 1.0366x; 1.0366x over previous
//
#include <hip/hip_runtime.h>
#include <hip/hip_bf16.h>
#include <math.h>

#define T_SEQ 4096
#define NH 16
#define HD 64
#define C_DIM 1024
#define N_QKV 3072

typedef __bf16 bf16x8 __attribute__((ext_vector_type(8)));
typedef __bf16 bf16x2 __attribute__((ext_vector_type(2)));
typedef float f32x4 __attribute__((ext_vector_type(4)));
typedef float f32x16 __attribute__((ext_vector_type(16)));
typedef unsigned short u16x8 __attribute__((ext_vector_type(8)));
typedef unsigned short u16x4 __attribute__((ext_vector_type(4)));
typedef unsigned int u32x4 __attribute__((ext_vector_type(4)));

__device__ __forceinline__ unsigned short f2bf(float f) {
  unsigned u = __builtin_bit_cast(unsigned, f);
  u += 0x7FFFu + ((u >> 16) & 1u);
  return (unsigned short)(u >> 16);
}

__device__ __forceinline__ bf16x8 lds_frag(const unsigned short* p) {
  return __builtin_bit_cast(bf16x8, *reinterpret_cast<const u16x8*>(p));
}

// async global->LDS, 16B per lane; LDS dest = wave-uniform base + lane*16
__device__ __forceinline__ void gload_lds16(const unsigned short* g, unsigned short* l) {
  __builtin_amdgcn_global_load_lds(
      (const __attribute__((address_space(1))) unsigned int*)(uintptr_t)(const void*)g,
      (__attribute__((address_space(3))) unsigned int*)(uintptr_t)(void*)l, 16, 0, 0);
}

// ---------------------------------------------------------------- convert ----
__global__ void convert_kernel(const float* __restrict__ x,
                               const float* __restrict__ wqkv,
                               const float* __restrict__ wout,
                               unsigned short* __restrict__ xb,
                               unsigned short* __restrict__ wqkvb,
                               unsigned short* __restrict__ woutb) {
  const int NX = T_SEQ * C_DIM;
  const int NW = N_QKV * C_DIM;
  const int NO = C_DIM * C_DIM;
  const int NTOT = (NX + NW + NO) / 4;
  for (int idx = blockIdx.x * blockDim.x + threadIdx.x; idx < NTOT;
       idx += gridDim.x * blockDim.x) {
    int i = idx * 4;
    const float* src;
    unsigned short* dst;
    if (i < NX)            { src = x + i;                dst = xb + i; }
    else if (i < NX + NW)  { src = wqkv + (i - NX);      dst = wqkvb + (i - NX); }
    else                   { src = wout + (i - NX - NW); dst = woutb + (i - NX - NW); }
    float4 v = *reinterpret_cast<const float4*>(src);
    u16x4 o;
    o[0] = f2bf(v.x); o[1] = f2bf(v.y); o[2] = f2bf(v.z); o[3] = f2bf(v.w);
    *reinterpret_cast<u16x4*>(dst) = o;
  }
}

// ------------------------------------------------------------------- GEMM ----
// (r12/r15 proven: both operands staged via global_load_lds width=16 with
// source-side XOR swizzle; no XCD swizzle — problem is L3-fit, m160)
template <bool F32OUT>
__global__ __launch_bounds__(256) void gemm_bt(
    const unsigned short* __restrict__ A, const unsigned short* __restrict__ Bm,
    unsigned short* __restrict__ Cb, float* __restrict__ Cf,
    const float* __restrict__ bias, int M, int N, int K,
    int scale_cols, float ascale) {
  __shared__ __align__(16) unsigned short As[128 * 64];
  __shared__ __align__(16) unsigned short Bs[128 * 64];
  const int tid = threadIdx.x;
  const int lane = tid & 63, wid = tid >> 6;
  const int l15 = lane & 15, g = lane >> 4;
  const int nbn = N >> 7;
  const int bm = blockIdx.x / nbn, bn = blockIdx.x % nbn;
  const int wm = wid >> 1, wn = wid & 1;

  f32x4 acc[4][4];
  const f32x4 zero = {0.f, 0.f, 0.f, 0.f};
#pragma unroll
  for (int m = 0; m < 4; m++)
#pragma unroll
    for (int n = 0; n < 4; n++) acc[m][n] = zero;

  for (int k0 = 0; k0 < K; k0 += 64) {
    __syncthreads();
#pragma unroll
    for (int i = 0; i < 4; i++) {
      int c = tid + i * 256;
      int row = c >> 3, slot = c & 7;
      int col = slot ^ (row & 7);
      gload_lds16(A + (size_t)(bm * 128 + row) * K + k0 + col * 8, &As[c * 8]);
      gload_lds16(Bm + (size_t)(bn * 128 + row) * K + k0 + col * 8, &Bs[c * 8]);
    }
    __syncthreads();
#pragma unroll
    for (int kk = 0; kk < 2; kk++) {
      bf16x8 af[4], bfr[4];
#pragma unroll
      for (int m = 0; m < 4; m++) {
        int row = wm * 64 + m * 16 + l15;
        af[m] = lds_frag(reinterpret_cast<const unsigned short*>(
            reinterpret_cast<const char*>(As) + row * 128 + ((kk * 64 + g * 16) ^ ((l15 & 7) << 4))));
      }
#pragma unroll
      for (int n = 0; n < 4; n++) {
        int row = wn * 64 + n * 16 + l15;
        bfr[n] = lds_frag(reinterpret_cast<const unsigned short*>(
            reinterpret_cast<const char*>(Bs) + row * 128 + ((kk * 64 + g * 16) ^ ((l15 & 7) << 4))));
      }
#pragma unroll
      for (int m = 0; m < 4; m++)
#pragma unroll
        for (int n = 0; n < 4; n++)
          acc[m][n] = __builtin_amdgcn_mfma_f32_16x16x32_bf16(af[m], bfr[n], acc[m][n], 0, 0, 0);
    }
  }
#pragma unroll
  for (int m = 0; m < 4; m++) {
    int row0 = bm * 128 + wm * 64 + m * 16 + g * 4;
#pragma unroll
    for (int n = 0; n < 4; n++) {
      int col = bn * 128 + wn * 64 + n * 16 + l15;
      float bi = 0.f;
      if (F32OUT) bi = bias[col];
      float cs = (col < scale_cols) ? ascale : 1.0f;
#pragma unroll
      for (int r = 0; r < 4; r++) {
        float v = acc[m][n][r];
        if (F32OUT) Cf[(size_t)(row0 + r) * N + col] = v + bi;
        else        Cb[(size_t)(row0 + r) * N + col] = f2bf(v * cs);
      }
    }
  }
}

// -------------------------------------------------------------- attention ----
// (r15 proven: swapped-QK^T, 32x32x16 MFMA, fixed-max softmax, 64 q-rows/wave,
// 2-way KV-split, immediate PV, permlane32_swap exchange, K dbuf [32x72] +
// V^T dbuf [64x40], (256,2) -> 104 VGPR no spill)
__global__ __launch_bounds__(256, 2) void attn_kernel(
    const unsigned short* __restrict__ qkv,   // [T][3072] bf16, q pre-scaled
    unsigned short* __restrict__ attn) {      // [T][1024] bf16
  __shared__ __align__(16) unsigned short smem[2 * 2 * 4864];   // 38912 B
  const int tid = threadIdx.x;
  const int lane = tid & 63, wid = tid >> 6;
  const int qw = wid & 1, str = wid >> 1;
  const int stid = qw * 64 + lane;
  const int l31 = lane & 31, hi = lane >> 5;
  const int sw = (blockIdx.x & 7) * 64 + (blockIdx.x >> 3);
  const int h = sw >> 5;
  const int qb = sw & 31;
  const int t0 = qb * 128 + qw * 64;
  const int q = l31;
  const int kvbase = str * (T_SEQ / 2);
  const int NT = (T_SEQ / 2) / 32;              // 64 tiles of 32 keys

  unsigned short* Sbase = &smem[str * 2 * 4864];

  const int krow = stid >> 2, ks = stid & 3;        // K: row 0..31, 32B slot
  const int kp = stid & 15, vd0 = (stid >> 4) * 8;  // V: keys 2kp,2kp+1; 8 d's

  bf16x8 qf[2][4];
#pragma unroll
  for (int j = 0; j < 2; j++)
#pragma unroll
    for (int ds = 0; ds < 4; ds++) {
      const unsigned short* p =
          qkv + (size_t)(t0 + j * 32 + q) * N_QKV + h * HD + ds * 16 + hi * 8;
      qf[j][ds] = __builtin_bit_cast(bf16x8, *reinterpret_cast<const u16x8*>(p));
    }

  float l_run[2] = {0.f, 0.f};
  f32x16 o[2][2];
  const f32x16 zero16 = {0.f};
  o[0][0] = zero16; o[0][1] = zero16; o[1][0] = zero16; o[1][1] = zero16;
  f32x16 minit;
#pragma unroll
  for (int i = 0; i < 16; i++) minit[i] = -4.0f;  // fixed softmax shift

  u16x8 kreg[2], vreg[2];
  {  // prologue: loads for this stream's tile 0
    const unsigned short* kb = qkv + (size_t)(kvbase + krow) * N_QKV + C_DIM + h * HD + ks * 16;
    kreg[0] = *reinterpret_cast<const u16x8*>(kb);
    kreg[1] = *reinterpret_cast<const u16x8*>(kb + 8);
    const unsigned short* vb = qkv + (size_t)(kvbase + 2 * kp) * N_QKV + 2 * C_DIM + h * HD + vd0;
    vreg[0] = *reinterpret_cast<const u16x8*>(vb);
    vreg[1] = *reinterpret_cast<const u16x8*>(vb + N_QKV);
  }

  for (int t = 0; t < NT; t++) {
    unsigned short* Kb = Sbase + (t & 1) * 4864;
    unsigned short* Vb = Kb + 2304;
    *reinterpret_cast<u16x8*>(&Kb[krow * 72 + ks * 16]) = kreg[0];
    *reinterpret_cast<u16x8*>(&Kb[krow * 72 + ks * 16 + 8]) = kreg[1];
#pragma unroll
    for (int jj = 0; jj < 8; jj++) {
      unsigned pk = (unsigned)vreg[0][jj] | ((unsigned)vreg[1][jj] << 16);
      *reinterpret_cast<unsigned*>(&Vb[(vd0 + jj) * 40 + 2 * kp]) = pk;
    }
    if (t < NT - 1) {
      const int kv0 = kvbase + (t + 1) * 32;
      const unsigned short* kb = qkv + (size_t)(kv0 + krow) * N_QKV + C_DIM + h * HD + ks * 16;
      kreg[0] = *reinterpret_cast<const u16x8*>(kb);
      kreg[1] = *reinterpret_cast<const u16x8*>(kb + 8);
      const unsigned short* vb = qkv + (size_t)(kv0 + 2 * kp) * N_QKV + 2 * C_DIM + h * HD + vd0;
      vreg[0] = *reinterpret_cast<const u16x8*>(vb);
      vreg[1] = *reinterpret_cast<const u16x8*>(vb + N_QKV);
    }
    __syncthreads();

    f32x16 s[2];
    s[0] = minit; s[1] = minit;
    __builtin_amdgcn_s_setprio(1);
#pragma unroll
    for (int ds = 0; ds < 4; ds++) {
      bf16x8 kf = lds_frag(&Kb[l31 * 72 + ds * 16 + hi * 8]);
      s[0] = __builtin_amdgcn_mfma_f32_32x32x16_bf16(kf, qf[0][ds], s[0], 0, 0, 0);
      s[1] = __builtin_amdgcn_mfma_f32_32x32x16_bf16(kf, qf[1][ds], s[1], 0, 0, 0);
    }
    __builtin_amdgcn_s_setprio(0);

    unsigned wA[2][8];
#pragma unroll
    for (int j = 0; j < 2; j++) {
      float psum[8];
#pragma unroll
      for (int i = 0; i < 8; i++) {
        float pa = __builtin_amdgcn_exp2f(s[j][2 * i]);
        float pb = __builtin_amdgcn_exp2f(s[j][2 * i + 1]);
        bf16x2 pk = {(__bf16)pa, (__bf16)pb};
        wA[j][i] = __builtin_bit_cast(unsigned, pk);
        psum[i] = pa + pb;
      }
#pragma unroll
      for (int i = 0; i < 4; i++) psum[i] += psum[i + 4];
      l_run[j] += (psum[0] + psum[2]) + (psum[1] + psum[3]);
#pragma unroll
      for (int base = 0; base < 8; base += 4)
#pragma unroll
        for (int k = 0; k < 2; k++) {
          unsigned A = wA[j][base + k];
          unsigned B = wA[j][base + k + 2];
          asm("v_permlane32_swap_b32 %0, %1" : "+v"(A), "+v"(B));
          wA[j][base + k]     = A;
          wA[j][base + k + 2] = B;
        }
    }

    u32x4 g00 = {wA[0][0], wA[0][1], wA[0][2], wA[0][3]};
    u32x4 g01 = {wA[0][4], wA[0][5], wA[0][6], wA[0][7]};
    u32x4 g10 = {wA[1][0], wA[1][1], wA[1][2], wA[1][3]};
    u32x4 g11 = {wA[1][4], wA[1][5], wA[1][6], wA[1][7]};
    bf16x8 pf00 = __builtin_bit_cast(bf16x8, g00);
    bf16x8 pf01 = __builtin_bit_cast(bf16x8, g01);
    bf16x8 pf10 = __builtin_bit_cast(bf16x8, g10);
    bf16x8 pf11 = __builtin_bit_cast(bf16x8, g11);
    __builtin_amdgcn_s_setprio(1);
#pragma unroll
    for (int dblk = 0; dblk < 2; dblk++) {
      bf16x8 vf0 = lds_frag(&Vb[(dblk * 32 + l31) * 40 + hi * 8]);
      bf16x8 vf1 = lds_frag(&Vb[(dblk * 32 + l31) * 40 + 16 + hi * 8]);
      o[0][dblk] = __builtin_amdgcn_mfma_f32_32x32x16_bf16(vf0, pf00, o[0][dblk], 0, 0, 0);
      o[0][dblk] = __builtin_amdgcn_mfma_f32_32x32x16_bf16(vf1, pf01, o[0][dblk], 0, 0, 0);
      o[1][dblk] = __builtin_amdgcn_mfma_f32_32x32x16_bf16(vf0, pf10, o[1][dblk], 0, 0, 0);
      o[1][dblk] = __builtin_amdgcn_mfma_f32_32x32x16_bf16(vf1, pf11, o[1][dblk], 0, 0, 0);
    }
    __builtin_amdgcn_s_setprio(0);
  }

  // ---- merge the 2 KV-split partials through LDS (fixed max -> direct add)
  float* ob = reinterpret_cast<float*>(&smem[0]);
  float* lb = ob + 8192;
  const int midx = qw * 64 + lane;
#pragma unroll
  for (int j = 0; j < 2; j++) {
    __syncthreads();
    if (str == 1) {
#pragma unroll
      for (int dblk = 0; dblk < 2; dblk++)
#pragma unroll
        for (int r = 0; r < 16; r++)
          ob[(dblk * 16 + r) * 128 + midx] = o[j][dblk][r];
      lb[midx] = l_run[j];
    }
    __syncthreads();
    if (str == 0) {
#pragma unroll
      for (int dblk = 0; dblk < 2; dblk++)
#pragma unroll
        for (int r = 0; r < 16; r++)
          o[j][dblk][r] += ob[(dblk * 16 + r) * 128 + midx];
      l_run[j] += lb[midx];
    }
  }

  // ---- epilogue: attn[t][h*64 + d] = O^T[d][q] / l
  if (str == 0) {
#pragma unroll
    for (int j = 0; j < 2; j++) {
      float lr = l_run[j];
      float inv = 1.f / (lr + __shfl_xor(lr, 32));
      const int t = t0 + j * 32 + q;
#pragma unroll
      for (int dblk = 0; dblk < 2; dblk++)
#pragma unroll
        for (int qd = 0; qd < 4; qd++) {
          u16x4 w;
#pragma unroll
          for (int i = 0; i < 4; i++) w[i] = f2bf(o[j][dblk][qd * 4 + i] * inv);
          *reinterpret_cast<u16x4*>(
              &attn[(size_t)t * C_DIM + h * HD + dblk * 32 + qd * 8 + hi * 4]) = w;
        }
    }
  }
}

// ----------------------------------------------------------------- launch ----
extern "C" void kernel_launch(void* const* d_in, const int* in_sizes, int n_in,
                              void* d_out, int out_size, void* d_ws, size_t ws_size,
                              hipStream_t stream) {
  const float* x     = (const float*)d_in[0];
  const float* w_qkv = (const float*)d_in[1];
  const float* w_out = (const float*)d_in[2];
  const float* b_out = (const float*)d_in[3];
  float* out = (float*)d_out;
  char* ws = (char*)d_ws;
  unsigned short* xb    = (unsigned short*)(ws);
  unsigned short* wqkvb = (unsigned short*)(ws + (8u << 20));
  unsigned short* woutb = (unsigned short*)(ws + (14u << 20));
  unsigned short* qkvb  = (unsigned short*)(ws + (16u << 20));
  unsigned short* attnb = (unsigned short*)(ws + (40u << 20));

  const float QSCALE = 0.125f * 1.44269504f;  // fold /sqrt(64) and log2e into q

  convert_kernel<<<2048, 256, 0, stream>>>(x, w_qkv, w_out, xb, wqkvb, woutb);
  gemm_bt<false><<<768, 256, 0, stream>>>(xb, wqkvb, qkvb, nullptr, nullptr,
                                          T_SEQ, N_QKV, C_DIM, C_DIM, QSCALE);
  attn_kernel<<<512, 256, 0, stream>>>(qkvb, attnb);
  gemm_bt<true><<<256, 256, 0, stream>>>(attnb, woutb, nullptr, out, b_out,
                                         T_SEQ, C_DIM, C_DIM, 0, 1.0f);
}